// Round 4
// baseline (219.321 us; speedup 1.0000x reference)
//
#include <hip/hip_runtime.h>
#include <cstdint>

#define NB 256       // batch
#define ND 2048      // feature dim
#define NP 8192      // proxies
#define NEG_INF_F (-1e30f)
#define INV_TEMP (1.0f/0.07f)

typedef __attribute__((ext_vector_type(8))) short          short8;
typedef __attribute__((ext_vector_type(8))) unsigned short ushort8;
typedef __attribute__((ext_vector_type(4))) float          floatx4;

__device__ __forceinline__ unsigned short f2bf(float f) {
  unsigned u = __float_as_uint(f);
  return (unsigned short)((u + 0x7fffu + ((u >> 16) & 1u)) >> 16);  // RNE
}

// ---- prep: mem -> bf16 + f32 copy into d_out; feat -> bf16; zero accums --
__global__ __launch_bounds__(256)
void prep_kernel(const float* __restrict__ mem, const float* __restrict__ feat,
                 unsigned short* __restrict__ Mb, unsigned short* __restrict__ Fb,
                 float* __restrict__ memcopy /* = out+1, only 4B-aligned */,
                 float* __restrict__ acc, unsigned* __restrict__ counter) {
  const int b = blockIdx.x, t = threadIdx.x;
  if (b < 8192) {
    const float4* src = (const float4*)(mem + (size_t)b * ND) + 2 * t;
    float4 a = src[0], c = src[1];
    ushort8 r;
    r[0]=f2bf(a.x); r[1]=f2bf(a.y); r[2]=f2bf(a.z); r[3]=f2bf(a.w);
    r[4]=f2bf(c.x); r[5]=f2bf(c.y); r[6]=f2bf(c.z); r[7]=f2bf(c.w);
    *(ushort8*)(Mb + (size_t)b * ND + 8 * t) = r;
    float* dst = memcopy + (size_t)b * ND + 8 * t;   // 4B-aligned only -> dwords
    dst[0]=a.x; dst[1]=a.y; dst[2]=a.z; dst[3]=a.w;
    dst[4]=c.x; dst[5]=c.y; dst[6]=c.z; dst[7]=c.w;
  } else if (b < 8448) {
    const int i = (b - 8192) * 256 + t;              // 8-elem group
    const float4* src = (const float4*)feat + 2 * (size_t)i;
    float4 a = src[0], c = src[1];
    ushort8 r;
    r[0]=f2bf(a.x); r[1]=f2bf(a.y); r[2]=f2bf(a.z); r[3]=f2bf(a.w);
    r[4]=f2bf(c.x); r[5]=f2bf(c.y); r[6]=f2bf(c.z); r[7]=f2bf(c.w);
    *(ushort8*)(Fb + 8 * (size_t)i) = r;
  } else {
    if (t < 16) acc[t] = 0.f;
    if (t == 16) counter[0] = 0u;
  }
}

// ---------------- GEMM: S[i][p] = sum_k F[i][k] * Mem[p][k] ----------------
// BM=64, BN=128, BK=64, split-K=2 (R2 geometry: 512 blocks = 2/CU).
#define GLOAD_LDS16(g, l) __builtin_amdgcn_global_load_lds( \
  (const __attribute__((address_space(1))) unsigned int*)(g), \
  (__attribute__((address_space(3))) unsigned int*)(l), 16, 0, 0)

__global__ __launch_bounds__(256, 2)
void gemm_kernel(const unsigned short* __restrict__ Fb,
                 const unsigned short* __restrict__ Mb,
                 float* __restrict__ Sout) {
  __shared__ unsigned short sA[2][64 * 64];    // 8 KB each
  __shared__ unsigned short sB[2][128 * 64];   // 16 KB each
  const int tid  = threadIdx.x;
  const int wave = tid >> 6;
  const int lane = tid & 63;
  const int frow = lane & 15;
  const int kg   = lane >> 4;
  const int bn0  = blockIdx.x * 128;
  const int bm0  = blockIdx.y * 64;
  const size_t kofs = (size_t)blockIdx.z * 1024;

  const unsigned short* gA[2];
  #pragma unroll
  for (int q = 0; q < 2; ++q) {
    int c = q * 256 + tid, r = c >> 3, kc = (c & 7) ^ (r & 7);
    gA[q] = Fb + (size_t)(bm0 + r) * ND + kofs + kc * 8;
  }
  const unsigned short* gB[4];
  #pragma unroll
  for (int q = 0; q < 4; ++q) {
    int c = q * 256 + tid, r = c >> 3, kc = (c & 7) ^ (r & 7);
    gB[q] = Mb + (size_t)(bn0 + r) * ND + kofs + kc * 8;
  }
  const int ldsb = wave * 512;   // elems; + q*2048 per instruction

  int offA[4][2], offB[2][2];
  #pragma unroll
  for (int m = 0; m < 4; ++m)
    #pragma unroll
    for (int kf = 0; kf < 2; ++kf) {
      int r = m * 16 + frow, sc = (kf * 4 + kg) ^ (r & 7);
      offA[m][kf] = r * 64 + sc * 8;
    }
  #pragma unroll
  for (int n = 0; n < 2; ++n)
    #pragma unroll
    for (int kf = 0; kf < 2; ++kf) {
      int r = wave * 32 + n * 16 + frow, sc = (kf * 4 + kg) ^ (r & 7);
      offB[n][kf] = r * 64 + sc * 8;
    }

  floatx4 acc[4][2];
  #pragma unroll
  for (int m = 0; m < 4; ++m)
    #pragma unroll
    for (int n = 0; n < 2; ++n)
      #pragma unroll
      for (int r = 0; r < 4; ++r) acc[m][n][r] = 0.f;

  auto stage = [&](int buf, int kt) {
    int kk = kt * 64;
    #pragma unroll
    for (int q = 0; q < 2; ++q) GLOAD_LDS16(gA[q] + kk, &sA[buf][q * 2048 + ldsb]);
    #pragma unroll
    for (int q = 0; q < 4; ++q) GLOAD_LDS16(gB[q] + kk, &sB[buf][q * 2048 + ldsb]);
  };
  auto compute = [&](int buf) {
    short8 af[4][2], bf[2][2];
    #pragma unroll
    for (int m = 0; m < 4; ++m)
      #pragma unroll
      for (int kf = 0; kf < 2; ++kf) af[m][kf] = *(const short8*)&sA[buf][offA[m][kf]];
    #pragma unroll
    for (int n = 0; n < 2; ++n)
      #pragma unroll
      for (int kf = 0; kf < 2; ++kf) bf[n][kf] = *(const short8*)&sB[buf][offB[n][kf]];
    #pragma unroll
    for (int m = 0; m < 4; ++m)
      #pragma unroll
      for (int n = 0; n < 2; ++n) {
        acc[m][n] = __builtin_amdgcn_mfma_f32_16x16x32_bf16(af[m][0], bf[n][0], acc[m][n], 0, 0, 0);
        acc[m][n] = __builtin_amdgcn_mfma_f32_16x16x32_bf16(af[m][1], bf[n][1], acc[m][n], 0, 0, 0);
      }
  };

  stage(0, 0);
  __syncthreads();
  int cur = 0;
  for (int kt = 0; kt < 15; ++kt) {     // 1024/64 = 16 K-steps per slice
    stage(cur ^ 1, kt + 1);
    compute(cur);
    __syncthreads();
    cur ^= 1;
  }
  compute(cur);

  float* Sp = Sout + (size_t)blockIdx.z * ((size_t)NB * NP);
  #pragma unroll
  for (int m = 0; m < 4; ++m) {
    int row = bm0 + 16 * m + 4 * kg;             // C/D: row=(lane>>4)*4+r
    #pragma unroll
    for (int n = 0; n < 2; ++n) {
      int col = bn0 + wave * 32 + 16 * n + frow; // C/D: col=lane&15
      #pragma unroll
      for (int r = 0; r < 4; ++r)
        Sp[(size_t)(row + r) * NP + col] = acc[m][n][r];
    }
  }
}

// ---------------- per-row + fused finalize -------------------------------
// 512 threads (8 waves), 16 elems/thread: p = 16t + j.
// p%8 = j&7; cluster = p>>3 = 2t + (j>>3).
__global__ __launch_bounds__(512)
void row_kernel(const float* __restrict__ S,
                const int* __restrict__ label,
                const int* __restrict__ camid,
                const int* __restrict__ pcl,
                const int* __restrict__ epoch_p,
                const int* __restrict__ ilep_p,
                const int* __restrict__ k_p,
                float* __restrict__ acc /* sa[8], sb[8] */,
                unsigned* __restrict__ counter,
                float* __restrict__ out) {
  __shared__ float red[2][3][8];
  __shared__ unsigned sh_done;
  __shared__ float cnt8[8], gsum[16];
  const int i = blockIdx.x, t = threadIdx.x, w = t >> 6;
  const bool l0 = (t & 63) == 0;
  int ph = 0;

  auto bmax = [&](float x) -> float {
    #pragma unroll
    for (int o = 32; o; o >>= 1) x = fmaxf(x, __shfl_xor(x, o));
    if (l0) red[ph][0][w] = x;
    __syncthreads();
    float r = red[ph][0][t & 7];
    #pragma unroll
    for (int o = 4; o; o >>= 1) r = fmaxf(r, __shfl_xor(r, o));
    ph ^= 1;
    return r;
  };
  auto bsum2 = [&](float& x, float& y) {
    #pragma unroll
    for (int o = 32; o; o >>= 1) { x += __shfl_xor(x, o); y += __shfl_xor(y, o); }
    if (l0) { red[ph][0][w] = x; red[ph][1][w] = y; }
    __syncthreads();
    float rx = red[ph][0][t & 7], ry = red[ph][1][t & 7];
    #pragma unroll
    for (int o = 4; o; o >>= 1) { rx += __shfl_xor(rx, o); ry += __shfl_xor(ry, o); }
    ph ^= 1; x = rx; y = ry;
  };
  auto bsum3 = [&](float& x, float& y, float& z) {
    #pragma unroll
    for (int o = 32; o; o >>= 1) {
      x += __shfl_xor(x, o); y += __shfl_xor(y, o); z += __shfl_xor(z, o);
    }
    if (l0) { red[ph][0][w] = x; red[ph][1][w] = y; red[ph][2][w] = z; }
    __syncthreads();
    float rx = red[ph][0][t & 7], ry = red[ph][1][t & 7], rz = red[ph][2][t & 7];
    #pragma unroll
    for (int o = 4; o; o >>= 1) {
      rx += __shfl_xor(rx, o); ry += __shfl_xor(ry, o); rz += __shfl_xor(rz, o);
    }
    ph ^= 1; x = rx; y = ry; z = rz;
  };

  const float* r0 = S + (size_t)i * NP;
  const float* r1 = r0 + (size_t)NB * NP;
  float v[16];
  {
    const float4* a0 = (const float4*)(r0 + (t << 4));
    const float4* a1 = (const float4*)(r1 + (t << 4));
    #pragma unroll
    for (int q = 0; q < 4; ++q) {
      float4 x = a0[q], y = a1[q];
      v[4*q+0] = x.x + y.x; v[4*q+1] = x.y + y.y;
      v[4*q+2] = x.z + y.z; v[4*q+3] = x.w + y.w;
    }
  }
  const int camI = camid[i], clI = pcl[i], lab = label[i];
  const bool negL = (2 * t)     != clI;     // cluster of j<8 elems
  const bool negH = (2 * t + 1) != clI;     // cluster of j>=8 elems

  // ---- intra-camera CE: exactly 2 in-cam elems per thread ----
  float m1 = fmaxf(v[camI], v[camI + 8]);
  m1 = bmax(m1);
  float s1 = __expf((v[camI] - m1) * INV_TEMP) + __expf((v[camI + 8] - m1) * INV_TEMP);
  float tg = (t == (lab >> 4)) ? v[lab & 15] : 0.f;
  bsum2(s1, tg);
  const float ce_i = m1 * INV_TEMP + __logf(s1) - tg * INV_TEMP;

  // ---- inter-camera loss ----
  float li = 0.f;
  const bool inter = epoch_p[0] >= ilep_p[0];
  if (inter) {
    const float kneg = (float)k_p[0];
    unsigned kk[16];
    #pragma unroll
    for (int j = 0; j < 16; ++j) {
      unsigned u = __float_as_uint(v[j]);
      kk[j] = (u & 0x80000000u) ? ~u : (u | 0x80000000u);
    }
    // exact k-th largest among negatives: 2 bits per round, 3 counts/round
    unsigned tstar = 0u;
    for (int b = 30; b >= 0; b -= 2) {
      const unsigned c1 = tstar | (1u << b);
      const unsigned c2 = tstar | (2u << b);
      const unsigned c3 = tstar | (3u << b);
      float n1 = 0.f, n2 = 0.f, n3 = 0.f;
      #pragma unroll
      for (int j = 0; j < 16; ++j) {
        const bool ng = (j < 8) ? negL : negH;
        if (ng) {
          n1 += (kk[j] >= c1) ? 1.f : 0.f;
          n2 += (kk[j] >= c2) ? 1.f : 0.f;
          n3 += (kk[j] >= c3) ? 1.f : 0.f;
        }
      }
      bsum3(n1, n2, n3);
      if (n2 >= kneg)      tstar = (n3 >= kneg) ? c3 : c2;
      else if (n1 >= kneg) tstar = c1;
    }
    const float thr = __uint_as_float((tstar & 0x80000000u) ? (tstar ^ 0x80000000u) : ~tstar);

    float m2 = NEG_INF_F;
    unsigned posm = 0u, selm = 0u;
    #pragma unroll
    for (int j = 0; j < 16; ++j) {
      const bool ng = (j < 8) ? negL : negH;
      const bool pos = (!ng) && ((j & 7) != camI);
      const bool sel = pos || (ng && (v[j] < thr));   // strict <, ties dropped
      if (pos) posm |= 1u << j;
      if (sel) { selm |= 1u << j; m2 = fmaxf(m2, v[j]); }
    }
    m2 = bmax(m2);
    float s2 = 0.f, sp = 0.f, card = 0.f;
    #pragma unroll
    for (int j = 0; j < 16; ++j) {
      if ((selm >> j) & 1u) s2 += __expf((v[j] - m2) * INV_TEMP);
      if ((posm >> j) & 1u) { sp += v[j]; card += 1.f; }
    }
    bsum3(s2, sp, card);
    const float lse2 = m2 * INV_TEMP + __logf(s2);
    li = (card > 0.f) ? -(sp * INV_TEMP - card * lse2) / card : 0.f;
  }

  // ---- accumulate per-cam sums; last block computes the scalar loss ----
  if (t == 0) {
    atomicAdd(&acc[camI], ce_i);
    atomicAdd(&acc[8 + camI], li);
    __threadfence();
    sh_done = atomicAdd(counter, 1u);
  }
  __syncthreads();
  if (sh_done == NB - 1) {
    if (t < 8) cnt8[t] = 0.f;
    __syncthreads();
    if (t < NB) atomicAdd(&cnt8[camid[t]], 1.f);
    if (t < 16) gsum[t] = acc[t];
    __syncthreads();
    if (t == 0) {
      float l = 0.f;
      for (int c = 0; c < 8; ++c)
        if (cnt8[c] > 0.f) {
          l += gsum[c] / cnt8[c];
          if (inter) l += 0.5f * gsum[8 + c] / cnt8[c];
        }
      out[0] = l;
    }
  }
}

// ---------------- sequential EMA scatter update (scan semantics) ----------
__global__ __launch_bounds__(256)
void ema_kernel(const float* __restrict__ feat,
                const float* __restrict__ mem,
                const int* __restrict__ label,
                float* __restrict__ outmem) {
  __shared__ float red[4];
  __shared__ int slab[NB];
  const int b = blockIdx.x, t = threadIdx.x;
  slab[t] = label[t];                    // 256 threads == NB
  __syncthreads();
  const int y = slab[b];
  bool mine = true;
  for (int j = 0; j < b; ++j)
    if (slab[j] == y) { mine = false; break; }
  if (!mine) return;                     // block-uniform
  float m[8];
  #pragma unroll
  for (int q = 0; q < 8; ++q) m[q] = mem[(size_t)y * ND + q * 256 + t];
  for (int i = b; i < NB; ++i) {
    if (slab[i] != y) continue;          // block-uniform, LDS
    float ss = 0.f;
    #pragma unroll
    for (int q = 0; q < 8; ++q) {
      m[q] = 0.2f * m[q] + 0.8f * feat[(size_t)i * ND + q * 256 + t];
      ss += m[q] * m[q];
    }
    #pragma unroll
    for (int o = 32; o; o >>= 1) ss += __shfl_xor(ss, o);
    if ((t & 63) == 0) red[t >> 6] = ss;
    __syncthreads();
    ss = red[0] + red[1] + red[2] + red[3];
    __syncthreads();
    float inv = 1.f / sqrtf(ss);
    #pragma unroll
    for (int q = 0; q < 8; ++q) m[q] *= inv;
  }
  #pragma unroll
  for (int q = 0; q < 8; ++q) outmem[(size_t)y * ND + q * 256 + t] = m[q];
}

// --------------------------------------------------------------------------
extern "C" void kernel_launch(void* const* d_in, const int* in_sizes, int n_in,
                              void* d_out, int out_size, void* d_ws, size_t ws_size,
                              hipStream_t stream) {
  const float* feat = (const float*)d_in[0];
  const float* mem  = (const float*)d_in[1];
  const int* lab    = (const int*)d_in[2];
  const int* cam    = (const int*)d_in[3];
  const int* pcl    = (const int*)d_in[4];
  const int* ep     = (const int*)d_in[7];
  const int* ilep   = (const int*)d_in[8];
  const int* kp     = (const int*)d_in[9];
  float* out = (float*)d_out;

  // scratch in d_ws (~51.4 MB)
  char* ws = (char*)d_ws;
  unsigned short* Mb = (unsigned short*)(ws);               // 33,554,432 B
  unsigned short* Fb = (unsigned short*)(ws + 33554432);    //  1,048,576 B
  float*          S  = (float*)(ws + 34603008);             // 16,777,216 B
  float*          acc = (float*)(ws + 51380224);            // sa[8], sb[8]
  unsigned*       ctr = (unsigned*)(ws + 51380224 + 64);    // counter

  prep_kernel<<<8449, 256, 0, stream>>>(mem, feat, Mb, Fb, out + 1, acc, ctr);
  gemm_kernel<<<dim3(NP / 128, NB / 64, 2), 256, 0, stream>>>(Fb, Mb, S);
  row_kernel<<<NB, 512, 0, stream>>>(S, lab, cam, pcl, ep, ilep, kp, acc, ctr, out);
  ema_kernel<<<NB, 256, 0, stream>>>(feat, mem, lab, out + 1);
}

// Round 5
// 202.367 us; speedup vs baseline: 1.0838x; 1.0838x over previous
//
#include <hip/hip_runtime.h>
#include <cstdint>

#define NB 256       // batch
#define ND 2048      // feature dim
#define NP 8192      // proxies
#define NEG_INF_F (-1e30f)
#define INV_TEMP (1.0f/0.07f)

typedef __attribute__((ext_vector_type(8))) short          short8;
typedef __attribute__((ext_vector_type(8))) unsigned short ushort8;
typedef __attribute__((ext_vector_type(4))) float          floatx4;

__device__ __forceinline__ unsigned short f2bf(float f) {
  unsigned u = __float_as_uint(f);
  return (unsigned short)((u + 0x7fffu + ((u >> 16) & 1u)) >> 16);  // RNE
}

// ---- prep: mem -> bf16 + aligned f32 copy into d_out; feat -> bf16 -------
__global__ __launch_bounds__(256)
void prep_kernel(const float* __restrict__ mem, const float* __restrict__ feat,
                 unsigned short* __restrict__ Mb, unsigned short* __restrict__ Fb,
                 float* __restrict__ out /* base of d_out; copy goes to out+1 */,
                 float* __restrict__ acc, unsigned* __restrict__ counter) {
  __shared__ float row[ND];
  const int b = blockIdx.x, t = threadIdx.x;
  if (b < 8192) {
    const float4* src = (const float4*)(mem + (size_t)b * ND) + 2 * t;
    float4 a = src[0], c = src[1];
    ushort8 r;
    r[0]=f2bf(a.x); r[1]=f2bf(a.y); r[2]=f2bf(a.z); r[3]=f2bf(a.w);
    r[4]=f2bf(c.x); r[5]=f2bf(c.y); r[6]=f2bf(c.z); r[7]=f2bf(c.w);
    *(ushort8*)(Mb + (size_t)b * ND + 8 * t) = r;
    *(float4*)(row + 8 * t)     = a;
    *(float4*)(row + 8 * t + 4) = c;
    __syncthreads();
    // dst element d (0..2047) lives at out[1 + 2048b + d]; groups d=4q+3..4q+6
    // land at out + 2048b + 4(q+1): 16B-aligned float4 stores.
    float* dst = out + 1 + (size_t)b * ND;
    {
      int q = t;                                  // groups 0..255
      float4 lo = *(const float4*)(row + 4 * q);
      float4 hi = *(const float4*)(row + 4 * q + 4);
      float4 w = {lo.w, hi.x, hi.y, hi.z};
      *(float4*)(dst + 4 * q + 3) = w;
    }
    if (t < 255) {
      int q = t + 256;                            // groups 256..510
      float4 lo = *(const float4*)(row + 4 * q);
      float4 hi = *(const float4*)(row + 4 * q + 4);
      float4 w = {lo.w, hi.x, hi.y, hi.z};
      *(float4*)(dst + 4 * q + 3) = w;
    }
    if (t == 0) { dst[0]=row[0]; dst[1]=row[1]; dst[2]=row[2]; dst[2047]=row[2047]; }
  } else if (b < 8448) {
    const int i = (b - 8192) * 256 + t;           // 8-elem group
    const float4* src = (const float4*)feat + 2 * (size_t)i;
    float4 a = src[0], c = src[1];
    ushort8 r;
    r[0]=f2bf(a.x); r[1]=f2bf(a.y); r[2]=f2bf(a.z); r[3]=f2bf(a.w);
    r[4]=f2bf(c.x); r[5]=f2bf(c.y); r[6]=f2bf(c.z); r[7]=f2bf(c.w);
    *(ushort8*)(Fb + 8 * (size_t)i) = r;
  } else {
    if (t < 16) acc[t] = 0.f;
    if (t == 16) counter[0] = 0u;
  }
}

// ---------------- GEMM: S[i][p] = sum_k F[i][k] * Mem[p][k] ----------------
// BM=64, BN=128, BK=64, split-K=2 (512 blocks = 2/CU).
#define GLOAD_LDS16(g, l) __builtin_amdgcn_global_load_lds( \
  (const __attribute__((address_space(1))) unsigned int*)(g), \
  (__attribute__((address_space(3))) unsigned int*)(l), 16, 0, 0)

__global__ __launch_bounds__(256, 2)
void gemm_kernel(const unsigned short* __restrict__ Fb,
                 const unsigned short* __restrict__ Mb,
                 float* __restrict__ Sout) {
  __shared__ unsigned short sA[2][64 * 64];    // 8 KB each
  __shared__ unsigned short sB[2][128 * 64];   // 16 KB each
  const int tid  = threadIdx.x;
  const int wave = tid >> 6;
  const int lane = tid & 63;
  const int frow = lane & 15;
  const int kg   = lane >> 4;
  const int bn0  = blockIdx.x * 128;
  const int bm0  = blockIdx.y * 64;
  const size_t kofs = (size_t)blockIdx.z * 1024;

  const unsigned short* gA[2];
  #pragma unroll
  for (int q = 0; q < 2; ++q) {
    int c = q * 256 + tid, r = c >> 3, kc = (c & 7) ^ (r & 7);
    gA[q] = Fb + (size_t)(bm0 + r) * ND + kofs + kc * 8;
  }
  const unsigned short* gB[4];
  #pragma unroll
  for (int q = 0; q < 4; ++q) {
    int c = q * 256 + tid, r = c >> 3, kc = (c & 7) ^ (r & 7);
    gB[q] = Mb + (size_t)(bn0 + r) * ND + kofs + kc * 8;
  }
  const int ldsb = wave * 512;   // elems; + q*2048 per instruction

  int offA[4][2], offB[2][2];
  #pragma unroll
  for (int m = 0; m < 4; ++m)
    #pragma unroll
    for (int kf = 0; kf < 2; ++kf) {
      int r = m * 16 + frow, sc = (kf * 4 + kg) ^ (r & 7);
      offA[m][kf] = r * 64 + sc * 8;
    }
  #pragma unroll
  for (int n = 0; n < 2; ++n)
    #pragma unroll
    for (int kf = 0; kf < 2; ++kf) {
      int r = wave * 32 + n * 16 + frow, sc = (kf * 4 + kg) ^ (r & 7);
      offB[n][kf] = r * 64 + sc * 8;
    }

  floatx4 acc[4][2];
  #pragma unroll
  for (int m = 0; m < 4; ++m)
    #pragma unroll
    for (int n = 0; n < 2; ++n)
      #pragma unroll
      for (int r = 0; r < 4; ++r) acc[m][n][r] = 0.f;

  auto stage = [&](int buf, int kt) {
    int kk = kt * 64;
    #pragma unroll
    for (int q = 0; q < 2; ++q) GLOAD_LDS16(gA[q] + kk, &sA[buf][q * 2048 + ldsb]);
    #pragma unroll
    for (int q = 0; q < 4; ++q) GLOAD_LDS16(gB[q] + kk, &sB[buf][q * 2048 + ldsb]);
  };
  auto compute = [&](int buf) {
    short8 af[4][2], bf[2][2];
    #pragma unroll
    for (int m = 0; m < 4; ++m)
      #pragma unroll
      for (int kf = 0; kf < 2; ++kf) af[m][kf] = *(const short8*)&sA[buf][offA[m][kf]];
    #pragma unroll
    for (int n = 0; n < 2; ++n)
      #pragma unroll
      for (int kf = 0; kf < 2; ++kf) bf[n][kf] = *(const short8*)&sB[buf][offB[n][kf]];
    #pragma unroll
    for (int m = 0; m < 4; ++m)
      #pragma unroll
      for (int n = 0; n < 2; ++n) {
        acc[m][n] = __builtin_amdgcn_mfma_f32_16x16x32_bf16(af[m][0], bf[n][0], acc[m][n], 0, 0, 0);
        acc[m][n] = __builtin_amdgcn_mfma_f32_16x16x32_bf16(af[m][1], bf[n][1], acc[m][n], 0, 0, 0);
      }
  };

  stage(0, 0);
  __syncthreads();
  int cur = 0;
  for (int kt = 0; kt < 15; ++kt) {     // 1024/64 = 16 K-steps per slice
    stage(cur ^ 1, kt + 1);
    compute(cur);
    __syncthreads();
    cur ^= 1;
  }
  compute(cur);

  float* Sp = Sout + (size_t)blockIdx.z * ((size_t)NB * NP);
  #pragma unroll
  for (int m = 0; m < 4; ++m) {
    int row = bm0 + 16 * m + 4 * kg;             // C/D: row=(lane>>4)*4+r
    #pragma unroll
    for (int n = 0; n < 2; ++n) {
      int col = bn0 + wave * 32 + 16 * n + frow; // C/D: col=lane&15
      #pragma unroll
      for (int r = 0; r < 4; ++r)
        Sp[(size_t)(row + r) * NP + col] = acc[m][n][r];
    }
  }
}

// ---------------- per-row + fused finalize -------------------------------
// 512 threads (8 waves), 16 elems/thread: p = 16t + j.
// p%8 = j&7; cluster = p>>3 = 2t + (j>>3).
__global__ __launch_bounds__(512)
void row_kernel(const float* __restrict__ S,
                const int* __restrict__ label,
                const int* __restrict__ camid,
                const int* __restrict__ pcl,
                const int* __restrict__ epoch_p,
                const int* __restrict__ ilep_p,
                const int* __restrict__ k_p,
                float* __restrict__ acc /* sa[8], sb[8] */,
                unsigned* __restrict__ counter,
                float* __restrict__ out) {
  __shared__ float red[2][3][8];
  __shared__ unsigned hist[256];
  __shared__ unsigned bc_d, bc_k;
  __shared__ unsigned sh_done;
  __shared__ float cnt8[8], gsum[16];
  const int i = blockIdx.x, t = threadIdx.x, w = t >> 6;
  const bool l0 = (t & 63) == 0;
  int ph = 0;

  auto bmax = [&](float x) -> float {
    #pragma unroll
    for (int o = 32; o; o >>= 1) x = fmaxf(x, __shfl_xor(x, o));
    if (l0) red[ph][0][w] = x;
    __syncthreads();
    float r = red[ph][0][t & 7];
    #pragma unroll
    for (int o = 4; o; o >>= 1) r = fmaxf(r, __shfl_xor(r, o));
    ph ^= 1;
    return r;
  };
  auto bsum2 = [&](float& x, float& y) {
    #pragma unroll
    for (int o = 32; o; o >>= 1) { x += __shfl_xor(x, o); y += __shfl_xor(y, o); }
    if (l0) { red[ph][0][w] = x; red[ph][1][w] = y; }
    __syncthreads();
    float rx = red[ph][0][t & 7], ry = red[ph][1][t & 7];
    #pragma unroll
    for (int o = 4; o; o >>= 1) { rx += __shfl_xor(rx, o); ry += __shfl_xor(ry, o); }
    ph ^= 1; x = rx; y = ry;
  };
  auto bsum3 = [&](float& x, float& y, float& z) {
    #pragma unroll
    for (int o = 32; o; o >>= 1) {
      x += __shfl_xor(x, o); y += __shfl_xor(y, o); z += __shfl_xor(z, o);
    }
    if (l0) { red[ph][0][w] = x; red[ph][1][w] = y; red[ph][2][w] = z; }
    __syncthreads();
    float rx = red[ph][0][t & 7], ry = red[ph][1][t & 7], rz = red[ph][2][t & 7];
    #pragma unroll
    for (int o = 4; o; o >>= 1) {
      rx += __shfl_xor(rx, o); ry += __shfl_xor(ry, o); rz += __shfl_xor(rz, o);
    }
    ph ^= 1; x = rx; y = ry; z = rz;
  };

  const float* r0 = S + (size_t)i * NP;
  const float* r1 = r0 + (size_t)NB * NP;
  float v[16];
  {
    const float4* a0 = (const float4*)(r0 + (t << 4));
    const float4* a1 = (const float4*)(r1 + (t << 4));
    #pragma unroll
    for (int q = 0; q < 4; ++q) {
      float4 x = a0[q], y = a1[q];
      v[4*q+0] = x.x + y.x; v[4*q+1] = x.y + y.y;
      v[4*q+2] = x.z + y.z; v[4*q+3] = x.w + y.w;
    }
  }
  const int camI = camid[i], clI = pcl[i], lab = label[i];
  const bool negL = (2 * t)     != clI;     // cluster of j<8 elems
  const bool negH = (2 * t + 1) != clI;     // cluster of j>=8 elems

  // ---- intra-camera CE: exactly 2 in-cam elems per thread ----
  float m1 = fmaxf(v[camI], v[camI + 8]);
  m1 = bmax(m1);
  float s1 = __expf((v[camI] - m1) * INV_TEMP) + __expf((v[camI + 8] - m1) * INV_TEMP);
  float tg = (t == (lab >> 4)) ? v[lab & 15] : 0.f;
  bsum2(s1, tg);
  const float ce_i = m1 * INV_TEMP + __logf(s1) - tg * INV_TEMP;

  // ---- inter-camera loss ----
  float li = 0.f;
  const bool inter = epoch_p[0] >= ilep_p[0];
  if (inter) {
    unsigned kk[16];
    #pragma unroll
    for (int j = 0; j < 16; ++j) {
      unsigned u = __float_as_uint(v[j]);
      kk[j] = (u & 0x80000000u) ? ~u : (u | 0x80000000u);
    }
    // exact k-th largest among negatives: 4-round byte radix select.
    // Invariant: krem = remaining rank within keys matching `prefix` high bits.
    unsigned prefix = 0u, krem = (unsigned)k_p[0];
    #pragma unroll
    for (int round = 0; round < 4; ++round) {
      const int sh = 24 - 8 * round;
      if (t < 256) hist[t] = 0u;
      __syncthreads();
      if (round == 0) {
        #pragma unroll
        for (int j = 0; j < 16; ++j) {
          const bool ng = (j < 8) ? negL : negH;
          if (ng) atomicAdd(&hist[kk[j] >> 24], 1u);
        }
      } else {
        #pragma unroll
        for (int j = 0; j < 16; ++j) {
          const bool ng = (j < 8) ? negL : negH;
          if (ng && ((kk[j] >> (sh + 8)) == (prefix >> (sh + 8))))
            atomicAdd(&hist[(kk[j] >> sh) & 255u], 1u);
        }
      }
      __syncthreads();
      if (t < 64) {                    // wave 0: suffix-scan, pick digit
        unsigned h0 = hist[4*t], h1 = hist[4*t+1], h2 = hist[4*t+2], h3 = hist[4*t+3];
        unsigned s = h0 + h1 + h2 + h3;
        unsigned suf = s;              // inclusive suffix sum across lanes
        #pragma unroll
        for (int o = 1; o < 64; o <<= 1) {
          unsigned g = __shfl_down(suf, o);
          if (t + o < 64) suf += g;
        }
        const unsigned above = suf - s;          // count in lanes > t
        const unsigned ge3 = above + h3, ge2 = ge3 + h2, ge1 = ge2 + h1, ge0 = ge1 + h0;
        int dsel = -1; unsigned sub = 0u;
        if      (ge3 >= krem && above < krem) { dsel = 3; sub = above; }
        else if (ge2 >= krem && ge3  < krem) { dsel = 2; sub = ge3; }
        else if (ge1 >= krem && ge2  < krem) { dsel = 1; sub = ge2; }
        else if (ge0 >= krem && ge1  < krem) { dsel = 0; sub = ge1; }
        if (dsel >= 0) {                         // exactly one lane
          bc_d = (unsigned)(4 * t + dsel);
          bc_k = krem - sub;
        }
      }
      __syncthreads();
      prefix |= bc_d << sh;
      krem = bc_k;
    }
    const unsigned tstar = prefix;
    const float thr = __uint_as_float((tstar & 0x80000000u) ? (tstar ^ 0x80000000u) : ~tstar);

    float m2 = NEG_INF_F;
    unsigned posm = 0u, selm = 0u;
    #pragma unroll
    for (int j = 0; j < 16; ++j) {
      const bool ng = (j < 8) ? negL : negH;
      const bool pos = (!ng) && ((j & 7) != camI);
      const bool sel = pos || (ng && (v[j] < thr));   // strict <, ties dropped
      if (pos) posm |= 1u << j;
      if (sel) { selm |= 1u << j; m2 = fmaxf(m2, v[j]); }
    }
    m2 = bmax(m2);
    float s2 = 0.f, sp = 0.f, card = 0.f;
    #pragma unroll
    for (int j = 0; j < 16; ++j) {
      if ((selm >> j) & 1u) s2 += __expf((v[j] - m2) * INV_TEMP);
      if ((posm >> j) & 1u) { sp += v[j]; card += 1.f; }
    }
    bsum3(s2, sp, card);
    const float lse2 = m2 * INV_TEMP + __logf(s2);
    li = (card > 0.f) ? -(sp * INV_TEMP - card * lse2) / card : 0.f;
  }

  // ---- accumulate per-cam sums; last block computes the scalar loss ----
  if (t == 0) {
    atomicAdd(&acc[camI], ce_i);
    atomicAdd(&acc[8 + camI], li);
    __threadfence();
    sh_done = atomicAdd(counter, 1u);
  }
  __syncthreads();
  if (sh_done == NB - 1) {
    if (t < 8) cnt8[t] = 0.f;
    __syncthreads();
    if (t < NB) atomicAdd(&cnt8[camid[t]], 1.f);
    if (t < 16) gsum[t] = acc[t];
    __syncthreads();
    if (t == 0) {
      float l = 0.f;
      for (int c = 0; c < 8; ++c)
        if (cnt8[c] > 0.f) {
          l += gsum[c] / cnt8[c];
          if (inter) l += 0.5f * gsum[8 + c] / cnt8[c];
        }
      out[0] = l;
    }
  }
}

// ---------------- sequential EMA scatter update (scan semantics) ----------
__global__ __launch_bounds__(256)
void ema_kernel(const float* __restrict__ feat,
                const float* __restrict__ mem,
                const int* __restrict__ label,
                float* __restrict__ outmem) {
  __shared__ float red[4];
  __shared__ int slab[NB];
  const int b = blockIdx.x, t = threadIdx.x;
  slab[t] = label[t];                    // 256 threads == NB
  __syncthreads();
  const int y = slab[b];
  bool mine = true;
  for (int j = 0; j < b; ++j)
    if (slab[j] == y) { mine = false; break; }
  if (!mine) return;                     // block-uniform
  float m[8];
  #pragma unroll
  for (int q = 0; q < 8; ++q) m[q] = mem[(size_t)y * ND + q * 256 + t];
  for (int i = b; i < NB; ++i) {
    if (slab[i] != y) continue;          // block-uniform, LDS
    float ss = 0.f;
    #pragma unroll
    for (int q = 0; q < 8; ++q) {
      m[q] = 0.2f * m[q] + 0.8f * feat[(size_t)i * ND + q * 256 + t];
      ss += m[q] * m[q];
    }
    #pragma unroll
    for (int o = 32; o; o >>= 1) ss += __shfl_xor(ss, o);
    if ((t & 63) == 0) red[t >> 6] = ss;
    __syncthreads();
    ss = red[0] + red[1] + red[2] + red[3];
    __syncthreads();
    float inv = 1.f / sqrtf(ss);
    #pragma unroll
    for (int q = 0; q < 8; ++q) m[q] *= inv;
  }
  #pragma unroll
  for (int q = 0; q < 8; ++q) outmem[(size_t)y * ND + q * 256 + t] = m[q];
}

// --------------------------------------------------------------------------
extern "C" void kernel_launch(void* const* d_in, const int* in_sizes, int n_in,
                              void* d_out, int out_size, void* d_ws, size_t ws_size,
                              hipStream_t stream) {
  const float* feat = (const float*)d_in[0];
  const float* mem  = (const float*)d_in[1];
  const int* lab    = (const int*)d_in[2];
  const int* cam    = (const int*)d_in[3];
  const int* pcl    = (const int*)d_in[4];
  const int* ep     = (const int*)d_in[7];
  const int* ilep   = (const int*)d_in[8];
  const int* kp     = (const int*)d_in[9];
  float* out = (float*)d_out;

  // scratch in d_ws (~51.4 MB)
  char* ws = (char*)d_ws;
  unsigned short* Mb = (unsigned short*)(ws);               // 33,554,432 B
  unsigned short* Fb = (unsigned short*)(ws + 33554432);    //  1,048,576 B
  float*          S  = (float*)(ws + 34603008);             // 16,777,216 B
  float*          acc = (float*)(ws + 51380224);            // sa[8], sb[8]
  unsigned*       ctr = (unsigned*)(ws + 51380224 + 64);    // counter

  prep_kernel<<<8449, 256, 0, stream>>>(mem, feat, Mb, Fb, out, acc, ctr);
  gemm_kernel<<<dim3(NP / 128, NB / 64, 2), 256, 0, stream>>>(Fb, Mb, S);
  row_kernel<<<NB, 512, 0, stream>>>(S, lab, cam, pcl, ep, ilep, kp, acc, ctr, out);
  ema_kernel<<<NB, 256, 0, stream>>>(feat, mem, lab, out + 1);
}